// Round 2
// baseline (16336.382 us; speedup 1.0000x reference)
//
#include <hip/hip_runtime.h>
#include <hip/hip_bf16.h>

#define TN 2048      // B*T tokens
#define TT 1024      // T
#define DM 768       // D
#define NH 12        // heads
#define HDM 64       // head dim
#define NE 4         // experts
#define NL 2         // layers
#define NV 50257     // vocab
#define FF 3072      // 4*D

// ---------------- embedding: x = wte[idx] + wpe[t] ----------------
__global__ __launch_bounds__(256) void embed_kernel(
    const int* __restrict__ idx, const float* __restrict__ wte,
    const float* __restrict__ wpe, float* __restrict__ X) {
  int n = blockIdx.x;            // token
  int t = n % TT;
  int tok = idx[n];
  const float* we = wte + (size_t)tok * DM;
  const float* pe = wpe + (size_t)t * DM;
  float* xr = X + (size_t)n * DM;
  for (int d = threadIdx.x; d < DM; d += 256)
    xr[d] = we[d] + pe[d];
}

// ---------------- LayerNorm ----------------
__global__ __launch_bounds__(256) void ln_kernel(
    const float* __restrict__ X, float* __restrict__ Y,
    const float* __restrict__ g, const float* __restrict__ b) {
  int row = blockIdx.x;
  const float* x = X + (size_t)row * DM;
  float* y = Y + (size_t)row * DM;
  float s = 0.f, ss = 0.f;
  for (int d = threadIdx.x; d < DM; d += 256) {
    float v = x[d]; s += v; ss += v * v;
  }
#pragma unroll
  for (int off = 32; off; off >>= 1) {
    s  += __shfl_xor(s, off);
    ss += __shfl_xor(ss, off);
  }
  __shared__ float sb[2][4];
  int w = threadIdx.x >> 6;
  if ((threadIdx.x & 63) == 0) { sb[0][w] = s; sb[1][w] = ss; }
  __syncthreads();
  s  = sb[0][0] + sb[0][1] + sb[0][2] + sb[0][3];
  ss = sb[1][0] + sb[1][1] + sb[1][2] + sb[1][3];
  float mean = s * (1.f / DM);
  float var = ss * (1.f / DM) - mean * mean;
  float rstd = rsqrtf(var + 1e-5f);
  for (int d = threadIdx.x; d < DM; d += 256)
    y[d] = (x[d] - mean) * rstd * g[d] + b[d];
}

// ---------------- gating: top-2 over E=4, softmax, coef ----------------
__global__ __launch_bounds__(64) void gate_kernel(
    const float* __restrict__ Xln, const float* __restrict__ gw,
    const float* __restrict__ nw, const float* __restrict__ noise,
    float* __restrict__ coef) {
  int n = blockIdx.x;
  const float* x = Xln + (size_t)n * DM;
  float ag[NE] = {0.f, 0.f, 0.f, 0.f};
  float an[NE] = {0.f, 0.f, 0.f, 0.f};
  for (int d = threadIdx.x; d < DM; d += 64) {
    float xv = x[d];
#pragma unroll
    for (int e = 0; e < NE; e++) {
      ag[e] += xv * gw[d * NE + e];
      an[e] += xv * nw[d * NE + e];
    }
  }
#pragma unroll
  for (int e = 0; e < NE; e++) {
#pragma unroll
    for (int off = 32; off; off >>= 1) {
      ag[e] += __shfl_xor(ag[e], off);
      an[e] += __shfl_xor(an[e], off);
    }
  }
  float lg[NE];
#pragma unroll
  for (int e = 0; e < NE; e++) {
    float s = an[e];
    float sp = fmaxf(s, 0.f) + log1pf(expf(-fabsf(s)));  // stable softplus
    lg[e] = ag[e] + noise[(size_t)n * NE + e] * sp;
  }
  // top-2, first-index tie-break (matches jax.lax.top_k)
  int i0 = 0; float m0 = lg[0];
#pragma unroll
  for (int e = 1; e < NE; e++) if (lg[e] > m0) { m0 = lg[e]; i0 = e; }
  int i1 = -1; float m1 = -1e30f;
#pragma unroll
  for (int e = 0; e < NE; e++) if (e != i0 && lg[e] > m1) { m1 = lg[e]; i1 = e; }
  float z = expf(m1 - m0);
  float inv = 1.f / (1.f + z);
  float w0 = inv, w1 = z * inv;
  if (threadIdx.x < NE) {
    int e = threadIdx.x;
    float c = (e == i0) ? w0 : ((e == i1) ? w1 : 0.f);
    coef[(size_t)n * NE + e] = c;
  }
}

// ---------------- attention: one wave per (b,h,t), online softmax ----------------
__global__ __launch_bounds__(256) void attn_kernel(
    const float* __restrict__ Q, const float* __restrict__ Kb,
    const float* __restrict__ Vb, float* __restrict__ O) {
  int wid = (blockIdx.x * 256 + threadIdx.x) >> 6;  // 0 .. B*NH*TT-1
  int lane = threadIdx.x & 63;
  int t = wid % TT;
  int h = (wid / TT) % NH;
  int b = wid / (TT * NH);
  size_t rowbase = ((size_t)(b * TT + t)) * DM + h * HDM;
  float q = Q[rowbase + lane] * 0.125f;   // 1/sqrt(64)
  float m = -1e30f, l = 0.f, o = 0.f;
  for (int j = 0; j <= t; j++) {
    size_t kb = ((size_t)(b * TT + j)) * DM + h * HDM + lane;
    float kv = Kb[kb];
    float vv = Vb[kb];
    float s = q * kv;
#pragma unroll
    for (int off = 32; off; off >>= 1) s += __shfl_xor(s, off);
    float mn = fmaxf(m, s);
    float p = expf(s - mn);
    float f = expf(m - mn);
    l = l * f + p;
    o = o * f + p * vv;
    m = mn;
  }
  O[rowbase + lane] = o / l;
}

// ---------------- residual add ----------------
__global__ __launch_bounds__(256) void add_kernel(
    float* __restrict__ X, const float* __restrict__ Y, int n) {
  int i = blockIdx.x * 256 + threadIdx.x;
  if (i < n) X[i] += Y[i];
}

// ---------------- generic tiled GEMM (all fp32) ----------------
// C[M,N] = A[M,K] @ B (NN: [K,N], NT: [N,K])
// epilogue: +bias(col), gelu, *rowscale[m*rs_stride], accumulate
#define BM 64
#define BN 64
#define BK 16
#define PAD 4

static __device__ __forceinline__ float geluf(float v) {
  const float c = 0.7978845608028654f;  // sqrt(2/pi)
  float t = tanhf(c * (v + 0.044715f * v * v * v));
  return 0.5f * v * (1.f + t);
}

__global__ __launch_bounds__(256) void gemm_kernel(
    const float* __restrict__ A, const float* __restrict__ B, float* __restrict__ C,
    int M, int N, int K, int transB,
    const float* __restrict__ bias, const float* __restrict__ rowscale, int rs_stride,
    int accumulate, int act) {
  __shared__ float As[BK][BM + PAD];
  __shared__ float Bs[BK][BN + PAD];
  int tid = threadIdx.x;
  int bm = blockIdx.y * BM;
  int bn = blockIdx.x * BN;
  int tx = tid & 15, ty = tid >> 4;
  int m0 = ty * 4, n0 = tx * 4;
  float acc[4][4] = {};

  for (int k0 = 0; k0 < K; k0 += BK) {
#pragma unroll
    for (int i = 0; i < 4; i++) {          // A tile: 64 rows x 16 k
      int e = tid + i * 256;
      int m = e >> 4, kk = e & 15;
      int gm = bm + m;
      float v = 0.f;
      if (gm < M) v = A[(size_t)gm * K + k0 + kk];
      As[kk][m] = v;
    }
    if (!transB) {
#pragma unroll
      for (int i = 0; i < 4; i++) {        // B tile: 16 k x 64 n
        int e = tid + i * 256;
        int kk = e >> 6, n = e & 63;
        int gn = bn + n;
        float v = 0.f;
        if (gn < N) v = B[(size_t)(k0 + kk) * N + gn];
        Bs[kk][n] = v;
      }
    } else {
#pragma unroll
      for (int i = 0; i < 4; i++) {
        int e = tid + i * 256;
        int n = e >> 4, kk = e & 15;
        int gn = bn + n;
        float v = 0.f;
        if (gn < N) v = B[(size_t)gn * K + k0 + kk];
        Bs[kk][n] = v;
      }
    }
    __syncthreads();
#pragma unroll
    for (int kk = 0; kk < BK; kk++) {
      float4 av = *(const float4*)&As[kk][m0];
      float4 bv = *(const float4*)&Bs[kk][n0];
      float a[4] = {av.x, av.y, av.z, av.w};
      float bb[4] = {bv.x, bv.y, bv.z, bv.w};
#pragma unroll
      for (int i = 0; i < 4; i++)
#pragma unroll
        for (int j = 0; j < 4; j++)
          acc[i][j] += a[i] * bb[j];
    }
    __syncthreads();
  }

#pragma unroll
  for (int i = 0; i < 4; i++) {
    int gm = bm + m0 + i;
    if (gm >= M) continue;
    float rs = rowscale ? rowscale[(size_t)gm * rs_stride] : 1.f;
#pragma unroll
    for (int j = 0; j < 4; j++) {
      int gn = bn + n0 + j;
      if (gn >= N) continue;
      float v = acc[i][j];
      if (bias) v += bias[gn];
      if (act == 1) v = geluf(v);
      v *= rs;
      size_t ci = (size_t)gm * N + gn;
      if (accumulate) C[ci] += v;
      else            C[ci] = v;
    }
  }
}

// ---------------- launch ----------------
extern "C" void kernel_launch(void* const* d_in, const int* in_sizes, int n_in,
                              void* d_out, int out_size, void* d_ws, size_t ws_size,
                              hipStream_t stream) {
  const int*   idx   = (const int*)d_in[0];
  const float* wte   = (const float*)d_in[1];
  const float* wpe   = (const float*)d_in[2];
  const float* ln1_g = (const float*)d_in[3];
  const float* ln1_b = (const float*)d_in[4];
  const float* ln2_g = (const float*)d_in[5];
  const float* ln2_b = (const float*)d_in[6];
  const float* lnf_g = (const float*)d_in[7];
  const float* lnf_b = (const float*)d_in[8];
  const float* Wk    = (const float*)d_in[9];
  const float* Wv    = (const float*)d_in[10];
  const float* Wq    = (const float*)d_in[11];
  const float* Wo    = (const float*)d_in[12];
  const float* gw    = (const float*)d_in[13];
  const float* nw    = (const float*)d_in[14];
  const float* fcw   = (const float*)d_in[15];
  const float* fcb   = (const float*)d_in[16];
  const float* pjw   = (const float*)d_in[17];
  const float* pjb   = (const float*)d_in[18];
  const float* noise = (const float*)d_in[19];

  const size_t ND = (size_t)TN * DM;
  float* x    = (float*)d_ws;
  float* xln  = x + ND;
  float* kbuf = xln + ND;
  float* vbuf = kbuf + ND;
  float* qbuf = vbuf + ND;
  float* obuf = qbuf + ND;
  float* moab = obuf + ND;
  float* hbuf = moab + ND;                 // TN*FF fp32
  float* coef = hbuf + (size_t)TN * FF;    // TN*NE fp32

  embed_kernel<<<TN, 256, 0, stream>>>(idx, wte, wpe, x);

  dim3 gD(DM / BN, TN / BM);
  dim3 gF(FF / BN, TN / BM);

  for (int l = 0; l < NL; l++) {
    ln_kernel<<<TN, 256, 0, stream>>>(x, xln, ln1_g + l * DM, ln1_b + l * DM);
    gate_kernel<<<TN, 64, 0, stream>>>(xln, gw + (size_t)l * DM * NE,
                                       nw + (size_t)l * DM * NE,
                                       noise + (size_t)l * TN * NE, coef);
    gemm_kernel<<<gD, 256, 0, stream>>>(xln, Wk + (size_t)l * DM * DM, kbuf,
                                        TN, DM, DM, 0, nullptr, nullptr, 0, 0, 0);
    gemm_kernel<<<gD, 256, 0, stream>>>(xln, Wv + (size_t)l * DM * DM, vbuf,
                                        TN, DM, DM, 0, nullptr, nullptr, 0, 0, 0);
    for (int e = 0; e < NE; e++) {
      gemm_kernel<<<gD, 256, 0, stream>>>(xln, Wq + ((size_t)l * NE + e) * DM * DM, qbuf,
                                          TN, DM, DM, 0, nullptr, nullptr, 0, 0, 0);
      attn_kernel<<<(2 * NH * TT) / 4, 256, 0, stream>>>(qbuf, kbuf, vbuf, obuf);
      gemm_kernel<<<gD, 256, 0, stream>>>(obuf, Wo + ((size_t)l * NE + e) * DM * DM, moab,
                                          TN, DM, DM, 0, nullptr, coef + e, NE,
                                          (e > 0) ? 1 : 0, 0);
    }
    add_kernel<<<(int)(ND / 256), 256, 0, stream>>>(x, moab, (int)ND);
    ln_kernel<<<TN, 256, 0, stream>>>(x, xln, ln2_g + l * DM, ln2_b + l * DM);
    gemm_kernel<<<gF, 256, 0, stream>>>(xln, fcw + (size_t)l * DM * FF, hbuf,
                                        TN, FF, DM, 0, fcb + (size_t)l * FF,
                                        nullptr, 0, 0, 1);
    gemm_kernel<<<gD, 256, 0, stream>>>(hbuf, pjw + (size_t)l * FF * DM, x,
                                        TN, DM, FF, 0, pjb + (size_t)l * DM,
                                        nullptr, 0, 1, 0);
  }

  ln_kernel<<<TN, 256, 0, stream>>>(x, xln, lnf_g, lnf_b);
  dim3 gV((NV + BN - 1) / BN, TN / BM);
  gemm_kernel<<<gV, 256, 0, stream>>>(xln, wte, (float*)d_out, TN, NV, DM, 1,
                                      nullptr, nullptr, 0, 0, 0);
}